// Round 7
// baseline (144.306 us; speedup 1.0000x reference)
//
#include <hip/hip_runtime.h>

#define NUM_CLASSES 80
#define N13 507
#define N26 2028
#define N52 8112
#define NANCH (N13 + N26 + N52)   // 10647
#define BATCH 64
#define MAXB 100
#define NB 3720                    // float-bit buckets: (bits>>14) - 0xFC00, scores in (0.5, 79)
#define BOFF 0xFC00u
#define LCAP 4096                  // LDS window capacity (power of 2)
#define LMASK (LCAP-1)

typedef unsigned long long u64;
typedef unsigned int u32;

// ---- workspace layout (bytes); ws_size ~664MB, we use <48MB ----
#define WS_SCORES 0u               // 64*10647*4  = 2.73 MB
#define WS_HIST   (4u<<20)         // 64*3720*4   = 952 KB (memset 0 per call)
#define WS_CURSOR (8u<<20)         // 952 KB (rewritten by K2 per call)
#define WS_TOTAL  (12u<<20)        // 256 B
#define WS_KEYS   (16u<<20)        // 64*10647*8  = 5.45 MB
#define WS_BOX    (32u<<20)        // 64*10647*16 = 10.9 MB

__device__ __forceinline__ u32 bkof_bits(u32 bits) {
    u32 bk = (bits >> 14) - BOFF;
    return (bk >= NB) ? (NB - 1) : bk;
}
__device__ __forceinline__ u32 bkof_key(u64 k) {
    u32 bk = (u32)(k >> 46) - BOFF;            // == (bits>>14) - BOFF
    return (bk >= NB) ? (NB - 1) : bk;
}

// ---------------- K1: score = p * (float)argmax(classes); + global histogram ----------------
__global__ __launch_bounds__(256) void score_kernel(
    const float* __restrict__ c13, const float* __restrict__ p13,
    const float* __restrict__ c26, const float* __restrict__ p26,
    const float* __restrict__ c52, const float* __restrict__ p52,
    float* __restrict__ scores, u32* __restrict__ hist)
{
    int n = blockIdx.x * blockDim.x + threadIdx.x;
    int b = blockIdx.y;
    if (n >= NANCH) return;
    const float* cbase; const float* pbase;
    if (n < N13)            { cbase = c13 + ((size_t)b*N13 + n) * NUM_CLASSES;           pbase = p13 + (size_t)b*N13 + n; }
    else if (n < N13+N26)   { cbase = c26 + ((size_t)b*N26 + (n-N13)) * NUM_CLASSES;     pbase = p26 + (size_t)b*N26 + (n-N13); }
    else                    { cbase = c52 + ((size_t)b*N52 + (n-N13-N26)) * NUM_CLASSES; pbase = p52 + (size_t)b*N52 + (n-N13-N26); }
    const float4* cp = (const float4*)cbase;
    float mx = -1.0f; int mi = 0;
    #pragma unroll
    for (int q = 0; q < NUM_CLASSES/4; ++q) {
        float4 v = cp[q];
        if (v.x > mx) { mx = v.x; mi = 4*q+0; }   // strict > keeps FIRST max (jnp.argmax)
        if (v.y > mx) { mx = v.y; mi = 4*q+1; }
        if (v.z > mx) { mx = v.z; mi = 4*q+2; }
        if (v.w > mx) { mx = v.w; mi = 4*q+3; }
    }
    float s = pbase[0] * (float)mi;
    scores[(size_t)b*NANCH + n] = s;
    if (s > 0.5f) atomicAdd(&hist[(size_t)b*NB + bkof_bits(__float_as_uint(s))], 1u);
}

__device__ __forceinline__ float4 load_box(const float* __restrict__ b13,
                                           const float* __restrict__ b26,
                                           const float* __restrict__ b52,
                                           int b, int n)
{
    if (n < N13)          return *(const float4*)(b13 + ((size_t)b*N13 + n)*4);
    else if (n < N13+N26) return *(const float4*)(b26 + ((size_t)b*N26 + (n-N13))*4);
    else                  return *(const float4*)(b52 + ((size_t)b*N52 + (n-N13-N26))*4);
}

// ---------------- K2: per-batch descending prefix: cursor[bk] = start_desc, totals[b] ----------
__global__ __launch_bounds__(1024) void prefix_kernel(
    const u32* __restrict__ hist, u32* __restrict__ cursor, u32* __restrict__ totals)
{
    const int b = blockIdx.x, tid = threadIdx.x, lane = tid & 63, wid = tid >> 6;
    __shared__ u32 wtot[16];
    const u32* hb = hist + (size_t)b * NB;
    u32 loc[4] = {0u,0u,0u,0u};
    if (tid < NB/4) {                            // NB % 4 == 0
        uint4 v = ((const uint4*)hb)[NB/4 - 1 - tid];
        loc[0]=v.w; loc[1]=v.z; loc[2]=v.y; loc[3]=v.x;   // loc[q] = hist[NB-1-(4*tid+q)]
    }
    u32 s4 = loc[0]+loc[1]+loc[2]+loc[3];
    u32 incl = s4;
    #pragma unroll
    for (int off = 1; off < 64; off <<= 1) {
        u32 v = __shfl_up(incl, off);
        if (lane >= off) incl += v;
    }
    if (lane == 63) wtot[wid] = incl;
    __syncthreads();
    u32 wexcl = 0u, total = 0u;
    #pragma unroll
    for (int w = 0; w < 16; ++w) { u32 t = wtot[w]; if (w < wid) wexcl += t; total += t; }
    u32 run = wexcl + (incl - s4);               // exclusive prefix over reversed buckets
    u32* cb = cursor + (size_t)b * NB;
    #pragma unroll
    for (int q = 0; q < 4; ++q) {
        int r = tid*4 + q;
        if (r < NB) { int bk = NB-1-r; cb[bk] = run; run += loc[q]; }
    }
    if (tid == 0) totals[b] = total;
}

// ---------------- K3: full-grid scatter of (key, box) into bucket-sorted global arrays --------
__global__ __launch_bounds__(256) void scatter_kernel(
    const float* __restrict__ scores,
    const float* __restrict__ b13, const float* __restrict__ b26, const float* __restrict__ b52,
    u32* __restrict__ cursor, u64* __restrict__ gkeys, float4* __restrict__ gbox)
{
    int n = blockIdx.x * blockDim.x + threadIdx.x;
    int b = blockIdx.y;
    if (n >= NANCH) return;
    float s = scores[(size_t)b*NANCH + n];
    if (s > 0.5f) {
        u32 bits = __float_as_uint(s);
        u32 pos = atomicAdd(&cursor[(size_t)b*NB + bkof_bits(bits)], 1u);
        gkeys[(size_t)b*NANCH + pos] = ((u64)bits << 32) | (u64)(0xFFFFFFFFu - (u32)n);
        gbox [(size_t)b*NANCH + pos] = load_box(b13, b26, b52, b, n);
    }
}

// ---------------- K4: windowed rank-permute + wave-parallel sequential-scan NMS ---------------
// greedy argmax-NMS == scan in (score desc, idx asc) order, accept iff IoU<=0.5 vs all accepted.
__global__ __launch_bounds__(1024) void nms_scan(
    const u64* __restrict__ gkeys, const float4* __restrict__ gbox,
    const u32* __restrict__ totals, float* __restrict__ out)
{
    const int b = blockIdx.x, tid = threadIdx.x, lane = tid & 63, wid = tid >> 6;
    __shared__ u64 keyr[LCAP];                  // 32 KB
    __shared__ float4 boxr[LCAP];               // 64 KB
    __shared__ float4 acc4[MAXB];
    __shared__ u64 sup_lds[16];
    __shared__ float outrec[MAXB][6];
    __shared__ int accN_s, Wmin_s;

    const u64*    kb  = gkeys + (size_t)b * NANCH;
    const float4* bbv = gbox  + (size_t)b * NANCH;
    const int total = (int)totals[b];
    if (tid == 0) accN_s = 0;

    int c = 0, We = 0, accN = 0;
    while (c < total && accN < MAXB) {
        if (c == We) {
            // ---- extend window [lo, hi): load, bucket-align end, rank-permute ----
            const int lo = We, hi = min(total, lo + LCAP);
            for (int p = lo + tid; p < hi; p += 1024) { keyr[p&LMASK] = kb[p]; boxr[p&LMASK] = bbv[p]; }
            if (tid == 0) Wmin_s = hi;
            __syncthreads();
            u64 kk[4]; float4 bx[4]; int tt[4];
            #pragma unroll
            for (int i = 0; i < 4; ++i) {
                int p = lo + tid + (i << 10); tt[i] = -1;
                if (p < hi) {
                    u64 key = keyr[p&LMASK];
                    u32 mybk = bkof_key(key);
                    int bs = p; while (bs > lo && bkof_key(keyr[(bs-1)&LMASK]) == mybk) --bs;
                    int be = p+1; while (be < hi && bkof_key(keyr[be&LMASK]) == mybk) ++be;
                    if (be == hi && hi < total) {
                        atomicMin(&Wmin_s, bs);  // bucket may straddle window end: exclude whole run
                    } else {
                        u32 rank = 0;
                        for (int q = bs; q < be; ++q) rank += (keyr[q&LMASK] > key) ? 1u : 0u;
                        kk[i] = key; bx[i] = boxr[p&LMASK]; tt[i] = bs + (int)rank;
                    }
                }
            }
            __syncthreads();                     // all rank reads done
            #pragma unroll
            for (int i = 0; i < 4; ++i) if (tt[i] >= 0) { keyr[tt[i]&LMASK] = kk[i]; boxr[tt[i]&LMASK] = bx[i]; }
            __syncthreads();
            We = Wmin_s;
            if (We == c) We = hi;                // unreachable guard: single bucket > LCAP elements
        }

        int m = We - c; if (m > 64) m = 64;
        u64 key = 0ull; float4 bb = make_float4(0.f,0.f,0.f,0.f);
        if (lane < m) { key = keyr[(c+lane)&LMASK]; bb = boxr[(c+lane)&LMASK]; }
        float cs  = __uint_as_float((u32)(key >> 32));
        float oy1 = bb.x, ox1 = bb.y, oy2 = bb.z, ox2 = bb.w;
        float y1 = fminf(oy1, oy2), y2 = fmaxf(oy1, oy2);
        float x1 = fminf(ox1, ox2), x2 = fmaxf(ox1, ox2);
        float ar = (y2-y1)*(x2-x1);

        // --- wave w checks accepted slice {w, w+16, ...}; no break -> ds_reads pipeline ---
        bool supp = (lane >= m);
        #pragma unroll 2
        for (int j = wid; j < accN; j += 16) {
            float4 aj = acc4[j];                 // broadcast read, conflict-free
            float jar = (aj.z - aj.x) * (aj.w - aj.y);   // bit-identical to ref's area
            float iy1=fmaxf(y1,aj.x), iy2=fminf(y2,aj.z);
            float ix1=fmaxf(x1,aj.y), ix2=fminf(x2,aj.w);
            float inter=fmaxf(iy2-iy1,0.f)*fmaxf(ix2-ix1,0.f);
            float un=(ar+jar)-inter;
            supp |= (un > 0.f) && (inter/un > 0.5f);
        }
        u64 bal = __ballot(supp);
        if (lane == 0) sup_lds[wid] = bal;
        __syncthreads();

        // --- wave 0: lazy in-order resolve on the OR of all partial ballots ---
        if (wid == 0) {
            u64 B = 0ull;
            #pragma unroll
            for (int w = 0; w < 16; ++w) B |= sup_lds[w];
            u64 valid_m = (m >= 64) ? ~0ull : ((1ull << m) - 1ull);
            u64 rem = (~B) & valid_m;
            while (rem && accN < MAXB) {
                int j = __builtin_ctzll(rem);    // next in sorted order
                float jy1=__shfl(y1,j), jx1=__shfl(x1,j), jy2=__shfl(y2,j);
                float jx2=__shfl(x2,j), jar=__shfl(ar,j);
                if (lane == j) {                 // accepting lane appends its own record
                    acc4[accN] = make_float4(y1, x1, y2, x2);
                    outrec[accN][0]=fminf(fmaxf(oy1,0.f),1.f);
                    outrec[accN][1]=fminf(fmaxf(ox1,0.f),1.f);
                    outrec[accN][2]=fminf(fmaxf(oy2,0.f),1.f);
                    outrec[accN][3]=fminf(fmaxf(ox2,0.f),1.f);
                    outrec[accN][4]=cs;
                    outrec[accN][5]=0.f;
                }
                float iy1=fmaxf(y1,jy1), iy2=fminf(y2,jy2);
                float ix1=fmaxf(x1,jx1), ix2=fminf(x2,jx2);
                float inter=fmaxf(iy2-iy1,0.f)*fmaxf(ix2-ix1,0.f);
                float un=(ar+jar)-inter;
                bool kill = (un > 0.f) && (inter/un > 0.5f);
                rem &= ~__ballot(kill);
                rem &= ~(1ull << j);
                accN++;
            }
            if (lane == 0) accN_s = accN;
        }
        __syncthreads();
        accN = accN_s;
        c += m;
    }

    __syncthreads();                             // accN_s visible even if loop never ran
    const int accNf = accN_s;
    float* outp = out + (size_t)b * (MAXB*6);
    for (int i = tid; i < MAXB*6; i += 1024) {
        int t = i / 6;
        outp[i] = (t < accNf) ? outrec[t][i % 6] : 0.f;
    }
    if (tid == 0) out[(size_t)BATCH*(MAXB*6) + b] = (float)accNf;
}

extern "C" void kernel_launch(void* const* d_in, const int* in_sizes, int n_in,
                              void* d_out, int out_size, void* d_ws, size_t ws_size,
                              hipStream_t stream)
{
    const float* bbox13 = (const float*)d_in[0];
    const float* p13    = (const float*)d_in[1];
    const float* c13    = (const float*)d_in[2];
    const float* bbox26 = (const float*)d_in[3];
    const float* p26    = (const float*)d_in[4];
    const float* c26    = (const float*)d_in[5];
    const float* bbox52 = (const float*)d_in[6];
    const float* p52    = (const float*)d_in[7];
    const float* c52    = (const float*)d_in[8];
    float* out = (float*)d_out;

    char* ws = (char*)d_ws;
    float*  scores = (float*) (ws + WS_SCORES);
    u32*    hist   = (u32*)   (ws + WS_HIST);
    u32*    cursor = (u32*)   (ws + WS_CURSOR);
    u32*    totals = (u32*)   (ws + WS_TOTAL);
    u64*    gkeys  = (u64*)   (ws + WS_KEYS);
    float4* gbox   = (float4*)(ws + WS_BOX);

    hipMemsetAsync(hist, 0, (size_t)BATCH * NB * sizeof(u32), stream);

    dim3 g1((NANCH + 255)/256, BATCH);
    score_kernel<<<g1, 256, 0, stream>>>(c13, p13, c26, p26, c52, p52, scores, hist);
    prefix_kernel<<<BATCH, 1024, 0, stream>>>(hist, cursor, totals);
    scatter_kernel<<<g1, 256, 0, stream>>>(scores, bbox13, bbox26, bbox52, cursor, gkeys, gbox);
    nms_scan<<<BATCH, 1024, 0, stream>>>(gkeys, gbox, totals, out);
}

// Round 8
// 112.854 us; speedup vs baseline: 1.2787x; 1.2787x over previous
//
#include <hip/hip_runtime.h>

#define NUM_CLASSES 80
#define N13 507
#define N26 2028
#define N52 8112
#define NANCH (N13 + N26 + N52)   // 10647
#define BATCH 64
#define MAXB 100
#define NB 3720                    // float-bit buckets: (bits>>14) - 0xFC00, scores in (0.5, 79)
#define BOFF 0xFC00u
#define KPT 11                     // ceil(NANCH/1024)
#define LCAP 1024                  // K4 window capacity (power of 2)
#define LMASK (LCAP-1)

typedef unsigned long long u64;
typedef unsigned int u32;

// ---- workspace layout (bytes) ----
#define WS_SCORES 0u               // 64*10647*4 = 2.73 MB
#define WS_TOTAL  (4u<<20)         // 256 B
#define WS_KEYS   (8u<<20)         // 64*10647*8 = 5.45 MB
#define WS_RS     (24u<<20)        // 64*10647*4 = 2.73 MB

__device__ __forceinline__ u32 bkof_bits(u32 bits) {
    u32 bk = (bits >> 14) - BOFF;
    return (bk >= NB) ? (NB - 1) : bk;
}

// ---------------- K1: score = p * (float)argmax(classes) — pure, HBM-roofline ----------------
__global__ __launch_bounds__(256) void score_kernel(
    const float* __restrict__ c13, const float* __restrict__ p13,
    const float* __restrict__ c26, const float* __restrict__ p26,
    const float* __restrict__ c52, const float* __restrict__ p52,
    float* __restrict__ scores)
{
    int n = blockIdx.x * blockDim.x + threadIdx.x;
    int b = blockIdx.y;
    if (n >= NANCH) return;
    const float* cbase; const float* pbase;
    if (n < N13)            { cbase = c13 + ((size_t)b*N13 + n) * NUM_CLASSES;           pbase = p13 + (size_t)b*N13 + n; }
    else if (n < N13+N26)   { cbase = c26 + ((size_t)b*N26 + (n-N13)) * NUM_CLASSES;     pbase = p26 + (size_t)b*N26 + (n-N13); }
    else                    { cbase = c52 + ((size_t)b*N52 + (n-N13-N26)) * NUM_CLASSES; pbase = p52 + (size_t)b*N52 + (n-N13-N26); }
    const float4* cp = (const float4*)cbase;
    float mx = -1.0f; int mi = 0;
    #pragma unroll
    for (int q = 0; q < NUM_CLASSES/4; ++q) {
        float4 v = cp[q];
        if (v.x > mx) { mx = v.x; mi = 4*q+0; }   // strict > keeps FIRST max (jnp.argmax)
        if (v.y > mx) { mx = v.y; mi = 4*q+1; }
        if (v.z > mx) { mx = v.z; mi = 4*q+2; }
        if (v.w > mx) { mx = v.w; mi = 4*q+3; }
    }
    scores[(size_t)b*NANCH + n] = pbase[0] * (float)mi;
}

__device__ __forceinline__ float4 load_box(const float* __restrict__ b13,
                                           const float* __restrict__ b26,
                                           const float* __restrict__ b52,
                                           int b, int n)
{
    if (n < N13)          return *(const float4*)(b13 + ((size_t)b*N13 + n)*4);
    else if (n < N13+N26) return *(const float4*)(b26 + ((size_t)b*N26 + (n-N13))*4);
    else                  return *(const float4*)(b52 + ((size_t)b*N52 + (n-N13-N26))*4);
}

// ------------- K2: per-batch LDS hist + prefix + scatter keys/runinfo to global ---------------
__global__ __launch_bounds__(1024) void sort_kernel(
    const float* __restrict__ scores,
    u64* __restrict__ gkeys, u32* __restrict__ grs, u32* __restrict__ totals)
{
    const int b = blockIdx.x, tid = threadIdx.x, lane = tid & 63, wid = tid >> 6;
    __shared__ u32 cnt[NB];                     // count -> start_desc -> cursor
    __shared__ u32 pk[NB];                      // (start_desc<<16) | count
    __shared__ u32 wtot[16];

    const float* sc = scores + (size_t)b * NANCH;
    float sreg[KPT];
    #pragma unroll
    for (int k = 0; k < KPT; ++k) {
        int n = tid + (k << 10);
        sreg[k] = (n < NANCH) ? sc[n] : 0.f;
    }
    for (int i = tid; i < NB; i += 1024) cnt[i] = 0u;
    __syncthreads();

    #pragma unroll
    for (int k = 0; k < KPT; ++k) {
        float s = sreg[k];
        if (s > 0.5f) atomicAdd(&cnt[bkof_bits(__float_as_uint(s))], 1u);
    }
    __syncthreads();

    // descending prefix via shfl wave-scan
    u32 loc[4]; u32 s4 = 0u;
    #pragma unroll
    for (int q = 0; q < 4; ++q) {
        int r = tid*4 + q;                       // reversed: r=0 -> bucket NB-1 (highest score)
        u32 v = (r < NB) ? cnt[NB-1-r] : 0u;
        loc[q] = v; s4 += v;
    }
    u32 incl = s4;
    #pragma unroll
    for (int off = 1; off < 64; off <<= 1) {
        u32 v = __shfl_up(incl, off);
        if (lane >= off) incl += v;
    }
    if (lane == 63) wtot[wid] = incl;
    __syncthreads();
    u32 wexcl = 0u, total = 0u;
    #pragma unroll
    for (int w = 0; w < 16; ++w) { u32 t = wtot[w]; if (w < wid) wexcl += t; total += t; }
    u32 run = wexcl + (incl - s4);
    __syncthreads();                             // all cnt reads (loc) done before overwrite
    #pragma unroll
    for (int q = 0; q < 4; ++q) {
        int r = tid*4 + q;
        if (r < NB) {
            int bk = NB-1-r;
            u32 c = loc[q];
            pk[bk] = (run << 16) | c;            // runstart | runlen
            cnt[bk] = run;                       // cursor starts at start_desc
            run += c;
        }
    }
    __syncthreads();

    u64* gk = gkeys + (size_t)b * NANCH;
    u32* gr = grs   + (size_t)b * NANCH;
    #pragma unroll
    for (int k = 0; k < KPT; ++k) {
        float s = sreg[k];
        if (s > 0.5f) {
            u32 bits = __float_as_uint(s);
            u32 bk = bkof_bits(bits);
            u32 pos = atomicAdd(&cnt[bk], 1u);
            gk[pos] = ((u64)bits << 32) | (u64)(0xFFFFFFFFu - (u32)(tid + (k<<10)));
            gr[pos] = pk[bk];
        }
    }
    if (tid == 0) totals[b] = total;
}

// ------------- K4: single-wave windowed rank + barrier-free sequential-scan NMS ---------------
// greedy argmax-NMS == scan in (score desc, idx asc) order, accept iff IoU<=0.5 vs all accepted.
__global__ __launch_bounds__(64) void nms_scan(
    const u64* __restrict__ gkeys, const u32* __restrict__ grs, const u32* __restrict__ totals,
    const float* __restrict__ b13, const float* __restrict__ b26, const float* __restrict__ b52,
    float* __restrict__ out)
{
    const int b = blockIdx.x, lane = threadIdx.x;
    __shared__ u64 keyr[LCAP];                  // 8 KB
    __shared__ u32 rsr[LCAP];                   // 4 KB
    __shared__ float4 acc4[MAXB];
    __shared__ float outrec[MAXB][6];

    const u64* kb = gkeys + (size_t)b * NANCH;
    const u32* rb = grs   + (size_t)b * NANCH;
    const int total = (int)totals[b];

    int c = 0, We = 0, accN = 0;
    bool have_pref = false;
    u64 pkey = 0ull; float4 pbb = make_float4(0.f,0.f,0.f,0.f);

    while (c < total && accN < MAXB) {
        if (c == We) {
            // ---- load window [lo,hi), align end to bucket runs, rank-permute ----
            const int lo = We, hi = min(total, lo + LCAP);
            for (int p = lo + lane; p < hi; p += 64) { keyr[p&LMASK] = kb[p]; rsr[p&LMASK] = rb[p]; }
            __asm__ volatile("s_waitcnt lgkmcnt(0)" ::: "memory");
            __builtin_amdgcn_sched_barrier(0);
            int Wend = hi;
            if (hi < total) {
                u32 pv = rsr[(hi-1)&LMASK];
                int rstart = (int)(pv >> 16), rlen = (int)(pv & 0xFFFFu);
                if (rstart + rlen > hi) Wend = (rstart > lo) ? rstart : hi;  // exclude straddler
            }
            u64 kk[LCAP/64]; int tt[LCAP/64];
            #pragma unroll
            for (int i = 0; i < LCAP/64; ++i) {
                int p = lo + lane + (i << 6); tt[i] = -1;
                if (p < Wend) {
                    u64 key = keyr[p&LMASK];
                    u32 pv  = rsr[p&LMASK];
                    int rstart = (int)(pv >> 16), rlen = (int)(pv & 0xFFFFu);
                    u32 rank = 0;
                    for (int q = rstart; q < rstart + rlen; ++q)
                        rank += (keyr[q&LMASK] > key) ? 1u : 0u;   // len known -> reads pipeline
                    kk[i] = key; tt[i] = rstart + (int)rank;
                }
            }
            // all reads above complete (program order) before any write below
            #pragma unroll
            for (int i = 0; i < LCAP/64; ++i) if (tt[i] >= 0) keyr[tt[i]&LMASK] = kk[i];
            __asm__ volatile("s_waitcnt lgkmcnt(0)" ::: "memory");
            __builtin_amdgcn_sched_barrier(0);
            We = Wend;
            have_pref = false;
        }

        int m = We - c; if (m > 64) m = 64;
        u64 key = 0ull; float4 bb = make_float4(0.f,0.f,0.f,0.f);
        if (have_pref) { key = pkey; bb = pbb; }
        else if (lane < m) {
            key = keyr[(c+lane)&LMASK];
            int n = (int)(0xFFFFFFFFu - (u32)(key & 0xFFFFFFFFull));
            bb = load_box(b13, b26, b52, b, n);
        }
        // prefetch next chunk's boxes (in flight during acc-check)
        {
            int nc = c + m, m2 = We - nc; if (m2 > 64) m2 = 64;
            have_pref = false;
            if (m2 > 0) {
                pkey = 0ull; pbb = make_float4(0.f,0.f,0.f,0.f);
                if (lane < m2) {
                    pkey = keyr[(nc+lane)&LMASK];
                    int n2 = (int)(0xFFFFFFFFu - (u32)(pkey & 0xFFFFFFFFull));
                    pbb = load_box(b13, b26, b52, b, n2);
                }
                have_pref = true;
            }
        }

        float cs  = __uint_as_float((u32)(key >> 32));
        float oy1 = bb.x, ox1 = bb.y, oy2 = bb.z, ox2 = bb.w;
        float y1 = fminf(oy1, oy2), y2 = fmaxf(oy1, oy2);
        float x1 = fminf(ox1, ox2), x2 = fmaxf(ox1, ox2);
        float ar = (y2-y1)*(x2-x1);

        // --- vs-accepted check: LDS broadcast reads, pipelined ---
        bool supp = (lane >= m);
        #pragma unroll 4
        for (int j = 0; j < accN; ++j) {
            float4 aj = acc4[j];
            float jar = (aj.z - aj.x) * (aj.w - aj.y);   // bit-identical to ref's area
            float iy1=fmaxf(y1,aj.x), iy2=fminf(y2,aj.z);
            float ix1=fmaxf(x1,aj.y), ix2=fminf(x2,aj.w);
            float inter=fmaxf(iy2-iy1,0.f)*fmaxf(ix2-ix1,0.f);
            float un=(ar+jar)-inter;
            supp |= (un > 0.f) && (inter/un > 0.5f);
        }

        // --- in-wave lazy resolve, no barriers ---
        u64 valid_m = (m >= 64) ? ~0ull : ((1ull << m) - 1ull);
        u64 rem = (~__ballot(supp)) & valid_m;
        while (rem && accN < MAXB) {
            int j = __builtin_ctzll(rem);        // next in sorted order
            float jy1=__shfl(y1,j), jx1=__shfl(x1,j), jy2=__shfl(y2,j);
            float jx2=__shfl(x2,j), jar=__shfl(ar,j);
            if (lane == j) {                     // accepting lane appends its own record
                acc4[accN] = make_float4(y1, x1, y2, x2);
                outrec[accN][0]=fminf(fmaxf(oy1,0.f),1.f);
                outrec[accN][1]=fminf(fmaxf(ox1,0.f),1.f);
                outrec[accN][2]=fminf(fmaxf(oy2,0.f),1.f);
                outrec[accN][3]=fminf(fmaxf(ox2,0.f),1.f);
                outrec[accN][4]=cs;
                outrec[accN][5]=0.f;
            }
            float iy1=fmaxf(y1,jy1), iy2=fminf(y2,jy2);
            float ix1=fmaxf(x1,jx1), ix2=fminf(x2,jx2);
            float inter=fmaxf(iy2-iy1,0.f)*fmaxf(ix2-ix1,0.f);
            float un=(ar+jar)-inter;
            bool kill = (un > 0.f) && (inter/un > 0.5f);
            rem &= ~__ballot(kill);
            rem &= ~(1ull << j);
            accN++;
        }
        __asm__ volatile("s_waitcnt lgkmcnt(0)" ::: "memory");  // acc4/outrec visible to next chunk
        __builtin_amdgcn_sched_barrier(0);
        c += m;
    }

    // ---- output write (single wave) ----
    float* outp = out + (size_t)b * (MAXB*6);
    for (int i = lane; i < MAXB*6; i += 64) {
        int t = i / 6;
        outp[i] = (t < accN) ? outrec[t][i % 6] : 0.f;
    }
    if (lane == 0) out[(size_t)BATCH*(MAXB*6) + b] = (float)accN;
}

extern "C" void kernel_launch(void* const* d_in, const int* in_sizes, int n_in,
                              void* d_out, int out_size, void* d_ws, size_t ws_size,
                              hipStream_t stream)
{
    const float* bbox13 = (const float*)d_in[0];
    const float* p13    = (const float*)d_in[1];
    const float* c13    = (const float*)d_in[2];
    const float* bbox26 = (const float*)d_in[3];
    const float* p26    = (const float*)d_in[4];
    const float* c26    = (const float*)d_in[5];
    const float* bbox52 = (const float*)d_in[6];
    const float* p52    = (const float*)d_in[7];
    const float* c52    = (const float*)d_in[8];
    float* out = (float*)d_out;

    char* ws = (char*)d_ws;
    float* scores = (float*)(ws + WS_SCORES);
    u32*   totals = (u32*)  (ws + WS_TOTAL);
    u64*   gkeys  = (u64*)  (ws + WS_KEYS);
    u32*   grs    = (u32*)  (ws + WS_RS);

    dim3 g1((NANCH + 255)/256, BATCH);
    score_kernel<<<g1, 256, 0, stream>>>(c13, p13, c26, p26, c52, p52, scores);
    sort_kernel<<<BATCH, 1024, 0, stream>>>(scores, gkeys, grs, totals);
    nms_scan<<<BATCH, 64, 0, stream>>>(gkeys, grs, totals, bbox13, bbox26, bbox52, out);
}

// Round 9
// 84.969 us; speedup vs baseline: 1.6983x; 1.3282x over previous
//
#include <hip/hip_runtime.h>

#define NUM_CLASSES 80
#define N13 507
#define N26 2028
#define N52 8112
#define NANCH (N13 + N26 + N52)   // 10647
#define BATCH 64
#define MAXB 100
#define NB 3720                    // float-bit buckets: (bits>>14) - 0xFC00, scores in (0.5, 79)
#define BOFF 0xFC00u
#define KPT 11                     // ceil(NANCH/1024)
#define TOPK 1024                  // region target size (scan needs ~456 for 100 accepts)
#define LCAP 4096                  // LDS ring capacity (power of 2)
#define LMASK (LCAP-1)

typedef unsigned long long u64;

// ---------------- Phase 1: per-anchor score = p * (float)argmax(classes) ----------------
__global__ __launch_bounds__(256) void score_kernel(
    const float* __restrict__ c13, const float* __restrict__ p13,
    const float* __restrict__ c26, const float* __restrict__ p26,
    const float* __restrict__ c52, const float* __restrict__ p52,
    float* __restrict__ scores)
{
    int n = blockIdx.x * blockDim.x + threadIdx.x;
    int b = blockIdx.y;
    if (n >= NANCH) return;
    const float* cbase; const float* pbase;
    if (n < N13)            { cbase = c13 + ((size_t)b*N13 + n) * NUM_CLASSES;           pbase = p13 + (size_t)b*N13 + n; }
    else if (n < N13+N26)   { cbase = c26 + ((size_t)b*N26 + (n-N13)) * NUM_CLASSES;     pbase = p26 + (size_t)b*N26 + (n-N13); }
    else                    { cbase = c52 + ((size_t)b*N52 + (n-N13-N26)) * NUM_CLASSES; pbase = p52 + (size_t)b*N52 + (n-N13-N26); }
    const float4* cp = (const float4*)cbase;
    float mx = -1.0f; int mi = 0;
    #pragma unroll
    for (int q = 0; q < NUM_CLASSES/4; ++q) {
        float4 v = cp[q];
        if (v.x > mx) { mx = v.x; mi = 4*q+0; }   // strict > keeps FIRST max (jnp.argmax)
        if (v.y > mx) { mx = v.y; mi = 4*q+1; }
        if (v.z > mx) { mx = v.z; mi = 4*q+2; }
        if (v.w > mx) { mx = v.w; mi = 4*q+3; }
    }
    scores[(size_t)b*NANCH + n] = pbase[0] * (float)mi;
}

__device__ __forceinline__ float4 load_box(const float* __restrict__ b13,
                                           const float* __restrict__ b26,
                                           const float* __restrict__ b52,
                                           int b, int n)
{
    if (n < N13)          return *(const float4*)(b13 + ((size_t)b*N13 + n)*4);
    else if (n < N13+N26) return *(const float4*)(b26 + ((size_t)b*N26 + (n-N13))*4);
    else                  return *(const float4*)(b52 + ((size_t)b*N52 + (n-N13-N26))*4);
}

// ---------------- Phase 2: top-K counting-sort by score (desc) + wave-parallel scan NMS -------
// greedy argmax-NMS == scan in (score desc, idx asc) order, accept iff IoU<=0.5 vs all accepted.
__global__ __launch_bounds__(1024) void nms_sort_scan(
    const float* __restrict__ scores,
    const float* __restrict__ b13, const float* __restrict__ b26, const float* __restrict__ b52,
    float* __restrict__ out)
{
    const int b    = blockIdx.x;
    const int tid  = threadIdx.x;
    const int lane = tid & 63;
    const int wid  = tid >> 6;

    __shared__ u64 lst[LCAP];                   // 32 KB ring of sorted candidates
    __shared__ unsigned int cnt[NB];            // 14.9 KB
    __shared__ unsigned int wtot[16];
    __shared__ float4 acc4[MAXB];               // accepted canonical boxes (y1,x1,y2,x2)
    __shared__ u64 sup_lds[2][16];              // parity-buffered supp ballots
    __shared__ u64 kmat[2][64];                 // parity-buffered in-chunk kill matrix rows
    __shared__ float outrec[MAXB][6];
    __shared__ int T_s, L_s;

    const float* sc = scores + (size_t)b * NANCH;

    // ---- hoist all score loads (independent, land under the LDS zeroing) ----
    float sreg[KPT];
    #pragma unroll
    for (int k = 0; k < KPT; ++k) {
        int n = tid + (k << 10);
        sreg[k] = (n < NANCH) ? sc[n] : 0.f;
    }

    for (int i = tid; i < NB; i += 1024) cnt[i] = 0u;
    __syncthreads();

    // ---- histogram from registers ----
    #pragma unroll
    for (int k = 0; k < KPT; ++k) {
        float s = sreg[k];
        if (s > 0.5f) {
            unsigned int bk = (__float_as_uint(s) >> 14) - BOFF;
            if (bk >= NB) bk = NB - 1;
            atomicAdd(&cnt[bk], 1u);
        }
    }
    __syncthreads();

    // ---- descending prefix (start_desc) via shfl wave-scan + crossing-bucket finder ----
    unsigned int loc[4]; unsigned int s4 = 0u;
    #pragma unroll
    for (int q = 0; q < 4; ++q) {
        int r = tid*4 + q;                       // reversed: r=0 -> bucket NB-1 (highest score)
        unsigned int v = (r < NB) ? cnt[NB-1-r] : 0u;
        loc[q] = v; s4 += v;
    }
    unsigned int incl = s4;
    #pragma unroll
    for (int off = 1; off < 64; off <<= 1) {
        unsigned int v = __shfl_up(incl, off);
        if (lane >= off) incl += v;
    }
    if (lane == 63) wtot[wid] = incl;
    __syncthreads();
    unsigned int wexcl = 0u, total = 0u;
    #pragma unroll
    for (int w = 0; w < 16; ++w) { unsigned int t = wtot[w]; if (w < wid) wexcl += t; total += t; }
    unsigned int run = wexcl + (incl - s4);      // exclusive prefix over reversed buckets
    if (tid == 0) { T_s = 0; L_s = (int)total; } // defaults if total <= TOPK
    __syncthreads();                             // cnt reads (loc) done; defaults visible
    #pragma unroll
    for (int q = 0; q < 4; ++q) {
        int r = tid*4 + q;
        if (r < NB) {
            int bk = NB-1-r;
            unsigned int c = loc[q];
            if (run < TOPK && run + c >= TOPK) { T_s = bk; L_s = (int)(run + c); }  // unique crosser
            cnt[bk] = run;                       // overwrite count with start_desc
            run += c;
        }
    }
    __syncthreads();
    const int total_i = (int)total;
    int Treg = T_s;
    int regionEnd = L_s;

    // ---- scatter region 1 (buckets >= Treg only, ~TOPK writes) ----
    #pragma unroll
    for (int k = 0; k < KPT; ++k) {
        float s = sreg[k];
        if (s > 0.5f) {
            unsigned int bits = __float_as_uint(s);
            unsigned int bk = (bits >> 14) - BOFF;
            if (bk >= NB) bk = NB - 1;
            if ((int)bk >= Treg) {
                unsigned int pos = atomicAdd(&cnt[bk], 1u);
                lst[pos & LMASK] = ((u64)bits << 32) | (u64)(0xFFFFFFFFu - (unsigned int)(tid + (k<<10)));
            }
        }
    }
    __syncthreads();
    // scattered buckets: cnt[bk] = end_desc; start = cnt[bk+1] (or 0). unscattered: still start_desc.

    // ---- rank-and-permute region [0, regionEnd): slot = start + #{bucket-mates larger} ----
    {
        u64 kk[4]; int tt[4];
        #pragma unroll
        for (int i = 0; i < 4; ++i) {
            int p = tid + (i << 10);
            tt[i] = -1; kk[i] = 0ull;
            if (p < regionEnd) {
                u64 key = lst[p & LMASK];
                unsigned int bk = (unsigned int)(key >> 46) - BOFF;
                if (bk >= NB) bk = NB - 1;
                unsigned int st = (bk+1 < NB) ? cnt[bk+1] : 0u;
                unsigned int e  = cnt[bk];
                unsigned int rank = 0u;
                for (unsigned int q = st; q < e; ++q) rank += (lst[q & LMASK] > key) ? 1u : 0u;
                kk[i] = key; tt[i] = (int)(st + rank);
            }
        }
        __syncthreads();
        #pragma unroll
        for (int i = 0; i < 4; ++i) if (tt[i] >= 0) lst[tt[i] & LMASK] = kk[i];
        __syncthreads();
    }

    // ---- wave-parallel chunked scan: 1 barrier/chunk, kill-matrix, redundant resolve ----
    int accN = 0;
    u64 key = 0ull; float4 bb = make_float4(0.f,0.f,0.f,0.f); float s = 0.f;
    if (lane < regionEnd) {
        key = lst[lane];
        unsigned int n = 0xFFFFFFFFu - (unsigned int)(key & 0xFFFFFFFFull);
        s = __uint_as_float((unsigned int)(key >> 32));
        bb = load_box(b13, b26, b52, b, (int)n);
    }

    int c = 0;
    while (c < total_i && accN < MAXB) {
        // ---- region extension (fallback; never taken for bench data) ----
        while (c + 64 > regionEnd && regionEnd < total_i) {
            int K2 = regionEnd + TOPK;
            if (tid == 0) { T_s = 0; L_s = total_i; }
            __syncthreads();
            for (int bk = tid; bk < Treg; bk += 1024) {
                unsigned int stv = cnt[bk];                                  // start_desc (untouched)
                unsigned int ev  = (bk == 0) ? (unsigned int)total_i : cnt[bk-1];  // end_desc[bk]
                if (stv < (unsigned int)K2 && ev >= (unsigned int)K2) { T_s = bk; L_s = (int)ev; }
            }
            __syncthreads();
            int T2 = T_s, L2 = L_s;
            #pragma unroll
            for (int k = 0; k < KPT; ++k) {
                float sv = sreg[k];
                if (sv > 0.5f) {
                    unsigned int bits = __float_as_uint(sv);
                    int bk = (int)((bits >> 14) - BOFF);
                    if (bk >= NB) bk = NB - 1;
                    if (bk >= T2 && bk < Treg) {
                        unsigned int pos = atomicAdd(&cnt[bk], 1u);
                        lst[pos & LMASK] = ((u64)bits << 32) | (u64)(0xFFFFFFFFu - (unsigned int)(tid + (k<<10)));
                    }
                }
            }
            __syncthreads();
            {
                u64 kk[4]; int tt[4];
                #pragma unroll
                for (int i = 0; i < 4; ++i) {
                    int p = regionEnd + tid + (i << 10);
                    tt[i] = -1; kk[i] = 0ull;
                    if (p < L2) {
                        u64 k2 = lst[p & LMASK];
                        unsigned int bk = (unsigned int)(k2 >> 46) - BOFF;
                        if (bk >= NB) bk = NB - 1;
                        unsigned int st = (bk+1 < NB) ? cnt[bk+1] : 0u;
                        unsigned int e  = cnt[bk];
                        unsigned int rank = 0u;
                        for (unsigned int q = st; q < e; ++q) rank += (lst[q & LMASK] > k2) ? 1u : 0u;
                        kk[i] = k2; tt[i] = (int)(st + rank);
                    }
                }
                __syncthreads();
                #pragma unroll
                for (int i = 0; i < 4; ++i) if (tt[i] >= 0) lst[tt[i] & LMASK] = kk[i];
                __syncthreads();
            }
            Treg = T2; regionEnd = L2;
            // reload current chunk (prefetched regs may be stale)
            key = 0ull; bb = make_float4(0.f,0.f,0.f,0.f); s = 0.f;
            if (c + lane < regionEnd) {
                key = lst[(c + lane) & LMASK];
                unsigned int n = 0xFFFFFFFFu - (unsigned int)(key & 0xFFFFFFFFull);
                s = __uint_as_float((unsigned int)(key >> 32));
                bb = load_box(b13, b26, b52, b, (int)n);
            }
        }

        int m = regionEnd - c; if (m > 64) m = 64;
        const int par = (c >> 6) & 1;            // parity for kmat/sup double-buffer
        float oy1 = bb.x, ox1 = bb.y, oy2 = bb.z, ox2 = bb.w, cs = s;
        float y1 = fminf(oy1, oy2), y2 = fmaxf(oy1, oy2);
        float x1 = fminf(ox1, ox2), x2 = fmaxf(ox1, ox2);
        float ar = (y2-y1)*(x2-x1);

        // prefetch next chunk (issued early; latency hides under check+build)
        int nc = c + 64;
        if (nc + lane < regionEnd) {
            key = lst[(nc + lane) & LMASK];
            unsigned int n = 0xFFFFFFFFu - (unsigned int)(key & 0xFFFFFFFFull);
            s = __uint_as_float((unsigned int)(key >> 32));
            bb = load_box(b13, b26, b52, b, (int)n);
        } else { s = 0.f; bb = make_float4(0.f,0.f,0.f,0.f); }

        // --- acc-check: wave w tests accepted slice {w, w+16, ...}; pipelined LDS reads ---
        bool supp = (lane >= m);
        #pragma unroll 2
        for (int j = wid; j < accN; j += 16) {
            float4 aj = acc4[j];                 // broadcast read, conflict-free
            float jar = (aj.z - aj.x) * (aj.w - aj.y);   // bit-identical to ref's area
            float iy1=fmaxf(y1,aj.x), iy2=fminf(y2,aj.z);
            float ix1=fmaxf(x1,aj.y), ix2=fminf(x2,aj.w);
            float inter=fmaxf(iy2-iy1,0.f)*fmaxf(ix2-ix1,0.f);
            float un=(ar+jar)-inter;
            supp |= (un > 0.f) && (inter/un > 0.5f);
        }
        if (lane == 0) sup_lds[par][wid] = 0ull;  // placeholder, overwritten below
        u64 bal = __ballot(supp);
        if (lane == 0) sup_lds[par][wid] = bal;

        // --- in-chunk kill matrix: wave w builds rows {w, w+16, w+32, w+48} (IoU symmetric) ---
        #pragma unroll
        for (int q = 0; q < 4; ++q) {
            int rr = wid + (q << 4);
            float ry1=__shfl(y1,rr), rx1=__shfl(x1,rr), ry2=__shfl(y2,rr), rx2=__shfl(x2,rr);
            float rar=__shfl(ar,rr);
            float iy1=fmaxf(y1,ry1), iy2=fminf(y2,ry2);
            float ix1=fmaxf(x1,rx1), ix2=fminf(x2,rx2);
            float inter=fmaxf(iy2-iy1,0.f)*fmaxf(ix2-ix1,0.f);
            float un=(ar+rar)-inter;
            u64 kb = __ballot((un > 0.f) && (inter/un > 0.5f));
            if (lane == 0) kmat[par][rr] = kb;
        }
        __syncthreads();                         // ONE barrier: ballots + kmat visible to all

        // --- redundant resolve (every wave; deterministic identical trajectory) ---
        u64 B = 0ull;
        #pragma unroll
        for (int w = 0; w < 16; ++w) B |= sup_lds[par][w];
        u64 valid_m = (m >= 64) ? ~0ull : ((1ull << m) - 1ull);
        u64 rem = (~B) & valid_m;
        while (rem && accN < MAXB) {
            int j = __builtin_ctzll(rem);        // next in sorted order
            u64 kj = kmat[par][j];               // row j: everyone j suppresses (incl. itself)
            if (lane == j) {                     // every wave's lane j writes identical data
                acc4[accN] = make_float4(y1, x1, y2, x2);
                outrec[accN][0]=fminf(fmaxf(oy1,0.f),1.f);
                outrec[accN][1]=fminf(fmaxf(ox1,0.f),1.f);
                outrec[accN][2]=fminf(fmaxf(oy2,0.f),1.f);
                outrec[accN][3]=fminf(fmaxf(ox2,0.f),1.f);
                outrec[accN][4]=cs;
                outrec[accN][5]=0.f;
            }
            rem &= ~kj;
            rem &= ~(1ull << j);
            accN++;
        }
        c += 64;                                 // no second barrier: acc4/outrec self-written
    }

    // ---- block-wide output write ----
    __syncthreads();
    float* outp = out + (size_t)b * (MAXB*6);
    for (int i = tid; i < MAXB*6; i += 1024) {
        int t = i / 6;
        outp[i] = (t < accN) ? outrec[t][i % 6] : 0.f;
    }
    if (tid == 0) out[(size_t)BATCH*(MAXB*6) + b] = (float)accN;
}

extern "C" void kernel_launch(void* const* d_in, const int* in_sizes, int n_in,
                              void* d_out, int out_size, void* d_ws, size_t ws_size,
                              hipStream_t stream)
{
    const float* bbox13 = (const float*)d_in[0];
    const float* p13    = (const float*)d_in[1];
    const float* c13    = (const float*)d_in[2];
    const float* bbox26 = (const float*)d_in[3];
    const float* p26    = (const float*)d_in[4];
    const float* c26    = (const float*)d_in[5];
    const float* bbox52 = (const float*)d_in[6];
    const float* p52    = (const float*)d_in[7];
    const float* c52    = (const float*)d_in[8];
    float* out    = (float*)d_out;
    float* scores = (float*)d_ws;   // 64*10647*4 = 2.7 MB

    dim3 g1((NANCH + 255)/256, BATCH);
    score_kernel<<<g1, 256, 0, stream>>>(c13, p13, c26, p26, c52, p52, scores);
    nms_sort_scan<<<BATCH, 1024, 0, stream>>>(scores, bbox13, bbox26, bbox52, out);
}

// Round 10
// 70.934 us; speedup vs baseline: 2.0344x; 1.1978x over previous
//
#include <hip/hip_runtime.h>

#define NUM_CLASSES 80
#define N13 507
#define N26 2028
#define N52 8112
#define NANCH (N13 + N26 + N52)   // 10647
#define BATCH 64
#define MAXB 100
#define NB 3720                    // float-bit buckets: (bits>>14) - 0xFC00, scores in (0.5, 79)
#define BOFF 0xFC00u
#define KPT 11                     // ceil(NANCH/1024)
#define TOPK 1024                  // region target size (scan needs ~456 for 100 accepts)
#define LCAP 4096                  // LDS ring capacity (power of 2)
#define LMASK (LCAP-1)
#define APB 64                     // anchors per 256-thread block (4 lanes/anchor)

typedef unsigned long long u64;

// ---------------- Phase 1: score = p * (float)argmax(classes), 4 lanes per anchor -------------
// Lane sub reads float4 at cbase + q*16 + sub*4: each 4-lane cluster = one full 64B line.
__global__ __launch_bounds__(256) void score_kernel(
    const float* __restrict__ c13, const float* __restrict__ p13,
    const float* __restrict__ c26, const float* __restrict__ p26,
    const float* __restrict__ c52, const float* __restrict__ p52,
    float* __restrict__ scores)
{
    int a   = blockIdx.x * APB + (threadIdx.x >> 2);
    int sub = threadIdx.x & 3;
    int b   = blockIdx.y;
    if (a >= NANCH) return;
    const float* cbase; const float* pbase;
    if (a < N13)            { cbase = c13 + ((size_t)b*N13 + a) * NUM_CLASSES;           pbase = p13 + (size_t)b*N13 + a; }
    else if (a < N13+N26)   { cbase = c26 + ((size_t)b*N26 + (a-N13)) * NUM_CLASSES;     pbase = p26 + (size_t)b*N26 + (a-N13); }
    else                    { cbase = c52 + ((size_t)b*N52 + (a-N13-N26)) * NUM_CLASSES; pbase = p52 + (size_t)b*N52 + (a-N13-N26); }
    float mx = -1.0f; int mi = 0;
    #pragma unroll
    for (int q = 0; q < 5; ++q) {
        float4 v = *(const float4*)(cbase + q*16 + sub*4);
        int cb = q*16 + sub*4;                   // classes ascend within each lane
        if (v.x > mx) { mx = v.x; mi = cb+0; }   // strict > keeps FIRST max
        if (v.y > mx) { mx = v.y; mi = cb+1; }
        if (v.z > mx) { mx = v.z; mi = cb+2; }
        if (v.w > mx) { mx = v.w; mi = cb+3; }
    }
    // merge across the 4-lane group: larger value wins; tie -> lower class index (jnp.argmax)
    #pragma unroll
    for (int off = 1; off < 4; off <<= 1) {
        float ov = __shfl_xor(mx, off);
        int   oi = __shfl_xor(mi, off);
        if (ov > mx || (ov == mx && oi < mi)) { mx = ov; mi = oi; }
    }
    if (sub == 0) scores[(size_t)b*NANCH + a] = pbase[0] * (float)mi;
}

__device__ __forceinline__ float4 load_box(const float* __restrict__ b13,
                                           const float* __restrict__ b26,
                                           const float* __restrict__ b52,
                                           int b, int n)
{
    if (n < N13)          return *(const float4*)(b13 + ((size_t)b*N13 + n)*4);
    else if (n < N13+N26) return *(const float4*)(b26 + ((size_t)b*N26 + (n-N13))*4);
    else                  return *(const float4*)(b52 + ((size_t)b*N52 + (n-N13-N26))*4);
}

// ---------------- Phase 2: top-K counting-sort by score (desc) + wave-parallel scan NMS -------
// (R6 version verbatim — best measured variant)
__global__ __launch_bounds__(1024) void nms_sort_scan(
    const float* __restrict__ scores,
    const float* __restrict__ b13, const float* __restrict__ b26, const float* __restrict__ b52,
    float* __restrict__ out)
{
    const int b    = blockIdx.x;
    const int tid  = threadIdx.x;
    const int lane = tid & 63;
    const int wid  = tid >> 6;

    __shared__ u64 lst[LCAP];                   // 32 KB ring of sorted candidates
    __shared__ unsigned int cnt[NB];            // 14.9 KB
    __shared__ unsigned int wtot[16];
    __shared__ float4 acc4[MAXB];               // accepted canonical boxes (y1,x1,y2,x2)
    __shared__ u64 sup_lds[16];
    __shared__ float outrec[MAXB][6];
    __shared__ int accN_s, T_s, L_s;

    const float* sc = scores + (size_t)b * NANCH;

    // ---- hoist all score loads (independent, land under the LDS zeroing) ----
    float sreg[KPT];
    #pragma unroll
    for (int k = 0; k < KPT; ++k) {
        int n = tid + (k << 10);
        sreg[k] = (n < NANCH) ? sc[n] : 0.f;
    }

    for (int i = tid; i < NB; i += 1024) cnt[i] = 0u;
    if (tid == 0) accN_s = 0;
    __syncthreads();

    // ---- histogram from registers ----
    #pragma unroll
    for (int k = 0; k < KPT; ++k) {
        float s = sreg[k];
        if (s > 0.5f) {
            unsigned int bk = (__float_as_uint(s) >> 14) - BOFF;
            if (bk >= NB) bk = NB - 1;
            atomicAdd(&cnt[bk], 1u);
        }
    }
    __syncthreads();

    // ---- descending prefix (start_desc) via shfl wave-scan + crossing-bucket finder ----
    unsigned int loc[4]; unsigned int s4 = 0u;
    #pragma unroll
    for (int q = 0; q < 4; ++q) {
        int r = tid*4 + q;                       // reversed: r=0 -> bucket NB-1 (highest score)
        unsigned int v = (r < NB) ? cnt[NB-1-r] : 0u;
        loc[q] = v; s4 += v;
    }
    unsigned int incl = s4;
    #pragma unroll
    for (int off = 1; off < 64; off <<= 1) {
        unsigned int v = __shfl_up(incl, off);
        if (lane >= off) incl += v;
    }
    if (lane == 63) wtot[wid] = incl;
    __syncthreads();
    unsigned int wexcl = 0u, total = 0u;
    #pragma unroll
    for (int w = 0; w < 16; ++w) { unsigned int t = wtot[w]; if (w < wid) wexcl += t; total += t; }
    unsigned int run = wexcl + (incl - s4);      // exclusive prefix over reversed buckets
    if (tid == 0) { T_s = 0; L_s = (int)total; } // defaults if total <= TOPK
    __syncthreads();                             // cnt reads (loc) done; defaults visible
    #pragma unroll
    for (int q = 0; q < 4; ++q) {
        int r = tid*4 + q;
        if (r < NB) {
            int bk = NB-1-r;
            unsigned int c = loc[q];
            if (run < TOPK && run + c >= TOPK) { T_s = bk; L_s = (int)(run + c); }  // unique crosser
            cnt[bk] = run;                       // overwrite count with start_desc
            run += c;
        }
    }
    __syncthreads();
    const int total_i = (int)total;
    int Treg = T_s;
    int regionEnd = L_s;

    // ---- scatter region 1 (buckets >= Treg only, ~TOPK writes) ----
    #pragma unroll
    for (int k = 0; k < KPT; ++k) {
        float s = sreg[k];
        if (s > 0.5f) {
            unsigned int bits = __float_as_uint(s);
            unsigned int bk = (bits >> 14) - BOFF;
            if (bk >= NB) bk = NB - 1;
            if ((int)bk >= Treg) {
                unsigned int pos = atomicAdd(&cnt[bk], 1u);
                lst[pos & LMASK] = ((u64)bits << 32) | (u64)(0xFFFFFFFFu - (unsigned int)(tid + (k<<10)));
            }
        }
    }
    __syncthreads();
    // scattered buckets: cnt[bk] = end_desc; start = cnt[bk+1] (or 0). unscattered: still start_desc.

    // ---- rank-and-permute region [0, regionEnd): slot = start + #{bucket-mates larger} ----
    {
        u64 kk[4]; int tt[4];
        #pragma unroll
        for (int i = 0; i < 4; ++i) {
            int p = tid + (i << 10);
            tt[i] = -1; kk[i] = 0ull;
            if (p < regionEnd) {
                u64 key = lst[p & LMASK];
                unsigned int bk = (unsigned int)(key >> 46) - BOFF;
                if (bk >= NB) bk = NB - 1;
                unsigned int st = (bk+1 < NB) ? cnt[bk+1] : 0u;
                unsigned int e  = cnt[bk];
                unsigned int rank = 0u;
                for (unsigned int q = st; q < e; ++q) rank += (lst[q & LMASK] > key) ? 1u : 0u;
                kk[i] = key; tt[i] = (int)(st + rank);
            }
        }
        __syncthreads();
        #pragma unroll
        for (int i = 0; i < 4; ++i) if (tt[i] >= 0) lst[tt[i] & LMASK] = kk[i];
        __syncthreads();
    }

    // ---- wave-parallel chunked scan ----
    int accN = 0;
    u64 key = 0ull; float4 bb = make_float4(0.f,0.f,0.f,0.f); float s = 0.f;
    if (lane < regionEnd) {
        key = lst[lane];
        unsigned int n = 0xFFFFFFFFu - (unsigned int)(key & 0xFFFFFFFFull);
        s = __uint_as_float((unsigned int)(key >> 32));
        bb = load_box(b13, b26, b52, b, (int)n);
    }

    int c = 0;
    while (c < total_i && accN < MAXB) {
        // ---- region extension (fallback; never taken for bench data) ----
        while (c + 64 > regionEnd && regionEnd < total_i) {
            int K2 = regionEnd + TOPK;
            if (tid == 0) { T_s = 0; L_s = total_i; }
            __syncthreads();
            for (int bk = tid; bk < Treg; bk += 1024) {
                unsigned int stv = cnt[bk];                                  // start_desc (untouched)
                unsigned int ev  = (bk == 0) ? (unsigned int)total_i : cnt[bk-1];  // end_desc[bk]
                if (stv < (unsigned int)K2 && ev >= (unsigned int)K2) { T_s = bk; L_s = (int)ev; }
            }
            __syncthreads();
            int T2 = T_s, L2 = L_s;
            #pragma unroll
            for (int k = 0; k < KPT; ++k) {
                float sv = sreg[k];
                if (sv > 0.5f) {
                    unsigned int bits = __float_as_uint(sv);
                    int bk = (int)((bits >> 14) - BOFF);
                    if (bk >= NB) bk = NB - 1;
                    if (bk >= T2 && bk < Treg) {
                        unsigned int pos = atomicAdd(&cnt[bk], 1u);
                        lst[pos & LMASK] = ((u64)bits << 32) | (u64)(0xFFFFFFFFu - (unsigned int)(tid + (k<<10)));
                    }
                }
            }
            __syncthreads();
            {
                u64 kk[4]; int tt[4];
                #pragma unroll
                for (int i = 0; i < 4; ++i) {
                    int p = regionEnd + tid + (i << 10);
                    tt[i] = -1; kk[i] = 0ull;
                    if (p < L2) {
                        u64 k2 = lst[p & LMASK];
                        unsigned int bk = (unsigned int)(k2 >> 46) - BOFF;
                        if (bk >= NB) bk = NB - 1;
                        unsigned int st = (bk+1 < NB) ? cnt[bk+1] : 0u;
                        unsigned int e  = cnt[bk];
                        unsigned int rank = 0u;
                        for (unsigned int q = st; q < e; ++q) rank += (lst[q & LMASK] > k2) ? 1u : 0u;
                        kk[i] = k2; tt[i] = (int)(st + rank);
                    }
                }
                __syncthreads();
                #pragma unroll
                for (int i = 0; i < 4; ++i) if (tt[i] >= 0) lst[tt[i] & LMASK] = kk[i];
                __syncthreads();
            }
            Treg = T2; regionEnd = L2;
            // reload current chunk (prefetched regs may be stale)
            key = 0ull; bb = make_float4(0.f,0.f,0.f,0.f); s = 0.f;
            if (c + lane < regionEnd) {
                key = lst[(c + lane) & LMASK];
                unsigned int n = 0xFFFFFFFFu - (unsigned int)(key & 0xFFFFFFFFull);
                s = __uint_as_float((unsigned int)(key >> 32));
                bb = load_box(b13, b26, b52, b, (int)n);
            }
        }

        int m = regionEnd - c; if (m > 64) m = 64;
        float oy1 = bb.x, ox1 = bb.y, oy2 = bb.z, ox2 = bb.w, cs = s;
        float y1 = fminf(oy1, oy2), y2 = fmaxf(oy1, oy2);
        float x1 = fminf(ox1, ox2), x2 = fmaxf(ox1, ox2);
        float ar = (y2-y1)*(x2-x1);

        // prefetch next chunk
        int nc = c + 64;
        if (nc + lane < regionEnd) {
            key = lst[(nc + lane) & LMASK];
            unsigned int n = 0xFFFFFFFFu - (unsigned int)(key & 0xFFFFFFFFull);
            s = __uint_as_float((unsigned int)(key >> 32));
            bb = load_box(b13, b26, b52, b, (int)n);
        } else { s = 0.f; bb = make_float4(0.f,0.f,0.f,0.f); }

        // --- wave w checks accepted slice {w, w+16, ...}; no break -> ds_reads pipeline ---
        bool supp = (lane >= m);
        #pragma unroll 2
        for (int j = wid; j < accN; j += 16) {
            float4 aj = acc4[j];                 // broadcast read, conflict-free
            float jar = (aj.z - aj.x) * (aj.w - aj.y);   // bit-identical to ref's area
            float iy1=fmaxf(y1,aj.x), iy2=fminf(y2,aj.z);
            float ix1=fmaxf(x1,aj.y), ix2=fminf(x2,aj.w);
            float inter=fmaxf(iy2-iy1,0.f)*fmaxf(ix2-ix1,0.f);
            float un=(ar+jar)-inter;
            supp |= (un > 0.f) && (inter/un > 0.5f);
        }
        u64 bal = __ballot(supp);
        if (lane == 0) sup_lds[wid] = bal;
        __syncthreads();

        // --- wave 0: lazy in-order resolve on the OR of all partial ballots ---
        if (wid == 0) {
            u64 B = 0ull;
            #pragma unroll
            for (int w = 0; w < 16; ++w) B |= sup_lds[w];
            u64 valid_m = (m >= 64) ? ~0ull : ((1ull << m) - 1ull);
            u64 rem = (~B) & valid_m;
            while (rem && accN < MAXB) {
                int j = __builtin_ctzll(rem);    // next in sorted order
                float jy1=__shfl(y1,j), jx1=__shfl(x1,j), jy2=__shfl(y2,j);
                float jx2=__shfl(x2,j), jar=__shfl(ar,j);
                if (lane == j) {                 // accepting lane appends its own record
                    acc4[accN] = make_float4(y1, x1, y2, x2);
                    outrec[accN][0]=fminf(fmaxf(oy1,0.f),1.f);
                    outrec[accN][1]=fminf(fmaxf(ox1,0.f),1.f);
                    outrec[accN][2]=fminf(fmaxf(oy2,0.f),1.f);
                    outrec[accN][3]=fminf(fmaxf(ox2,0.f),1.f);
                    outrec[accN][4]=cs;
                    outrec[accN][5]=0.f;
                }
                float iy1=fmaxf(y1,jy1), iy2=fminf(y2,jy2);
                float ix1=fmaxf(x1,jx1), ix2=fminf(x2,jx2);
                float inter=fmaxf(iy2-iy1,0.f)*fmaxf(ix2-ix1,0.f);
                float un=(ar+jar)-inter;
                bool kill = (un > 0.f) && (inter/un > 0.5f);
                rem &= ~__ballot(kill);
                rem &= ~(1ull << j);
                accN++;
            }
            if (lane == 0) accN_s = accN;
        }
        __syncthreads();
        accN = accN_s;
        c += 64;
    }

    // ---- block-wide output write ----
    const int accNf = accN_s;
    float* outp = out + (size_t)b * (MAXB*6);
    for (int i = tid; i < MAXB*6; i += 1024) {
        int t = i / 6;
        outp[i] = (t < accNf) ? outrec[t][i % 6] : 0.f;
    }
    if (tid == 0) out[(size_t)BATCH*(MAXB*6) + b] = (float)accNf;
}

extern "C" void kernel_launch(void* const* d_in, const int* in_sizes, int n_in,
                              void* d_out, int out_size, void* d_ws, size_t ws_size,
                              hipStream_t stream)
{
    const float* bbox13 = (const float*)d_in[0];
    const float* p13    = (const float*)d_in[1];
    const float* c13    = (const float*)d_in[2];
    const float* bbox26 = (const float*)d_in[3];
    const float* p26    = (const float*)d_in[4];
    const float* c26    = (const float*)d_in[5];
    const float* bbox52 = (const float*)d_in[6];
    const float* p52    = (const float*)d_in[7];
    const float* c52    = (const float*)d_in[8];
    float* out    = (float*)d_out;
    float* scores = (float*)d_ws;   // 64*10647*4 = 2.7 MB

    dim3 g1((NANCH + APB - 1)/APB, BATCH);
    score_kernel<<<g1, 256, 0, stream>>>(c13, p13, c26, p26, c52, p52, scores);
    nms_sort_scan<<<BATCH, 1024, 0, stream>>>(scores, bbox13, bbox26, bbox52, out);
}